// Round 4
// baseline (3638.391 us; speedup 1.0000x reference)
//
#include <hip/hip_runtime.h>
#include <hip/hip_bf16.h>
#include <math.h>

#define Bb   4
#define Tt   1024
#define Cc   768
#define Hh   12
#define Dd   64
#define Ll   12
#define Vv   10000
#define WTEe 704
#define MTOT 4096   // B*T

typedef __bf16 bf16x8 __attribute__((ext_vector_type(8)));
typedef float  f32x4  __attribute__((ext_vector_type(4)));
typedef unsigned short u16;

typedef const __attribute__((address_space(1))) void* gptr_t;
typedef __attribute__((address_space(3))) void* lptr_t;

__device__ inline void gload16(const void* g, void* l) {
    __builtin_amdgcn_global_load_lds((gptr_t)g, (lptr_t)l, 16, 0, 0);
}

__device__ inline u16 f2bf(float f) {
    unsigned int u = __float_as_uint(f);
    return (u16)((u + 0x7fffu + ((u >> 16) & 1u)) >> 16);   // RNE
}
__device__ inline float bf2f(u16 u) { return __uint_as_float(((unsigned)u) << 16); }

__device__ inline float gelu_f(float v) {
    // tanh-form GELU; |err| vs exact erf-GELU ~1e-3 << tolerance
    float t = v * (0.797884561f + 0.0356774081f * v * v);
    float e = __expf(2.f * t);
    float th = 1.f - 2.f / (e + 1.f);     // robust at e -> inf / 0
    return 0.5f * v * (1.f + th);
}

#define WAITVM(N) asm volatile("s_waitcnt vmcnt(" #N ")" ::: "memory")
#define SCHEDB()  __builtin_amdgcn_sched_barrier(0)
#define SBAR()    __builtin_amdgcn_s_barrier()

// ---------------------------------------------------------------------------
// float -> bf16 conversion
// ---------------------------------------------------------------------------
__global__ __launch_bounds__(256)
void convert_bf16(const float* __restrict__ in, u16* __restrict__ out, int n4)
{
    int i = blockIdx.x * 256 + threadIdx.x;
    if (i >= n4) return;
    float4 v = ((const float4*)in)[i];
    ushort4 o;
    o.x = f2bf(v.x); o.y = f2bf(v.y); o.z = f2bf(v.z); o.w = f2bf(v.w);
    ((ushort4*)out)[i] = o;
}

// ---------------------------------------------------------------------------
// Embedding (f32 residual stream)
// ---------------------------------------------------------------------------
__global__ __launch_bounds__(256)
void embed_kernel(const int* __restrict__ idx, const float* __restrict__ ts,
                  const float* __restrict__ wte, const float* __restrict__ freq,
                  const float* __restrict__ ph, const float* __restrict__ wpe,
                  float* __restrict__ x)
{
    const int bt  = blockIdx.x;
    const int t   = bt & (Tt - 1);
    const int tok = idx[bt];
    const float tv = ts[bt];
#pragma unroll
    for (int j = 0; j < 3; ++j) {
        int c = threadIdx.x + (j << 8);
        float val;
        if (c < WTEe) val = wte[(size_t)tok * WTEe + c];
        else {
            int e = c - WTEe;
            val = cosf(tv * freq[e] + ph[e]);
        }
        x[(size_t)bt * Cc + c] = val + wpe[(size_t)t * Cc + c];
    }
}

// ---------------------------------------------------------------------------
// LayerNorm: f32 in -> bf16 out
// ---------------------------------------------------------------------------
__global__ __launch_bounds__(256)
void ln_kernel(const float* __restrict__ x, const float* __restrict__ wt,
               const float* __restrict__ bs, u16* __restrict__ out)
{
    const int row = blockIdx.x;
    const int tid = threadIdx.x;
    const float* xr = x + (size_t)row * Cc;
    float v0 = xr[tid], v1 = xr[tid + 256], v2 = xr[tid + 512];
    float s = v0 + v1 + v2;
#pragma unroll
    for (int m = 32; m; m >>= 1) s += __shfl_xor(s, m);
    __shared__ float red[4];
    const int wv = tid >> 6;
    if ((tid & 63) == 0) red[wv] = s;
    __syncthreads();
    float mu = (red[0] + red[1] + red[2] + red[3]) * (1.f / 768.f);
    float d0 = v0 - mu, d1 = v1 - mu, d2 = v2 - mu;
    float s2 = d0 * d0 + d1 * d1 + d2 * d2;
#pragma unroll
    for (int m = 32; m; m >>= 1) s2 += __shfl_xor(s2, m);
    __syncthreads();
    if ((tid & 63) == 0) red[wv] = s2;
    __syncthreads();
    float var = (red[0] + red[1] + red[2] + red[3]) * (1.f / 768.f);
    float rs = rsqrtf(var + 1e-5f);
    u16* orow = out + (size_t)row * Cc;
    orow[tid]       = f2bf(d0 * rs * wt[tid]       + bs[tid]);
    orow[tid + 256] = f2bf(d1 * rs * wt[tid + 256] + bs[tid + 256]);
    orow[tid + 512] = f2bf(d2 * rs * wt[tid + 512] + bs[tid + 512]);
}

// ---------------------------------------------------------------------------
// bf16 GEMM: BM=BN=128, BK=32, 4 waves, fragment-major LDS, TRIPLE-buffered,
// counted vmcnt(4) + raw s_barrier (T3/T4): 1 tile-depth of loads stays in
// flight across the barrier; never vmcnt(0) in steady state.
// out[M,N] = A[M,K] @ W[N,K]^T (+bias)(+epilogue)
// EPI: 0 bias, 1 bias+f32 resid, 2 bias+GELU, 3 qkv (V cols -> vt[b,h,d,T])
// ---------------------------------------------------------------------------
__device__ inline void st_out(float* p, size_t o, float v) { p[o] = v; }
__device__ inline void st_out(u16*   p, size_t o, float v) { p[o] = f2bf(v); }

template<int EPI, typename OutT>
__global__ __launch_bounds__(256)
void gemm_bf16(const u16* __restrict__ A, const u16* __restrict__ W,
               const float* __restrict__ bias, const float* __restrict__ resid,
               OutT* __restrict__ out, u16* __restrict__ vt, int N, int K)
{
    __shared__ uint4 AF[3][8][64];
    __shared__ uint4 BF[3][8][64];
    const int tid  = threadIdx.x;
    const int lane = tid & 63;
    const int w    = tid >> 6;
    const int wr   = w >> 1, wc = w & 1;
    const int lq   = lane & 15, g = lane >> 4;
    const int m0   = blockIdx.x * 128, n0 = blockIdx.y * 128;

    const int arow0 = m0 + (2 * w) * 16 + lq;
    const int arow1 = arow0 + 16;
    int brow0 = n0 + (2 * w) * 16 + lq;
    int brow1 = brow0 + 16;
    brow0 = brow0 < N ? brow0 : N - 1;
    brow1 = brow1 < N ? brow1 : N - 1;
    const u16* ap0 = A + (size_t)arow0 * K + g * 8;
    const u16* ap1 = A + (size_t)arow1 * K + g * 8;
    const u16* bp0 = W + (size_t)brow0 * K + g * 8;
    const u16* bp1 = W + (size_t)brow1 * K + g * 8;

    f32x4 acc[4][4] = {};
    const int nk = K >> 5;   // >= 24 for all our shapes

#define GSTAGE(s, sl) do { int kk_ = (s) << 5;                      \
        gload16(ap0 + kk_, &AF[sl][2 * w][lane]);                   \
        gload16(ap1 + kk_, &AF[sl][2 * w + 1][lane]);               \
        gload16(bp0 + kk_, &BF[sl][2 * w][lane]);                   \
        gload16(bp1 + kk_, &BF[sl][2 * w + 1][lane]); } while (0)

    GSTAGE(0, 0);
    GSTAGE(1, 1);
    WAITVM(4);          // tile 0 landed; tile 1 may still fly
    SCHEDB();
    SBAR();
    SCHEDB();

    int sl = 0;
    for (int t = 0; t < nk; ++t) {
        int sl2 = sl + 2; if (sl2 >= 3) sl2 -= 3;
        if (t + 2 < nk) GSTAGE(t + 2, sl2);

        bf16x8 af[4], bfr[4];
#pragma unroll
        for (int mi = 0; mi < 4; ++mi)
            af[mi] = __builtin_bit_cast(bf16x8, AF[sl][wr * 4 + mi][lane]);
#pragma unroll
        for (int ni = 0; ni < 4; ++ni)
            bfr[ni] = __builtin_bit_cast(bf16x8, BF[sl][wc * 4 + ni][lane]);
        __builtin_amdgcn_s_setprio(1);
#pragma unroll
        for (int mi = 0; mi < 4; ++mi)
#pragma unroll
            for (int ni = 0; ni < 4; ++ni)
                acc[mi][ni] = __builtin_amdgcn_mfma_f32_16x16x32_bf16(
                    af[mi], bfr[ni], acc[mi][ni], 0, 0, 0);
        __builtin_amdgcn_s_setprio(0);

        if (t + 2 < nk) { WAITVM(4); }   // t+1 landed, t+2 still in flight
        else           { WAITVM(0); }    // tail: drain
        SCHEDB();
        SBAR();
        SCHEDB();
        sl = (sl + 1 == 3) ? 0 : sl + 1;
    }
#undef GSTAGE

    if (EPI == 3 && n0 >= 1536) {        // V block -> transposed vt[b,h,d,T]
#pragma unroll
        for (int mi = 0; mi < 4; ++mi)
#pragma unroll
            for (int ni = 0; ni < 4; ++ni) {
                int col = n0 + wc * 64 + ni * 16 + lq;
                int c2  = col - 1536;
                int hh  = c2 >> 6, dd = c2 & 63;
                int row = m0 + wr * 64 + mi * 16 + g * 4;
                int bb  = row >> 10, tr = row & 1023;
                float bv = bias[col];
                ushort4 o;
                o.x = f2bf(acc[mi][ni][0] + bv);
                o.y = f2bf(acc[mi][ni][1] + bv);
                o.z = f2bf(acc[mi][ni][2] + bv);
                o.w = f2bf(acc[mi][ni][3] + bv);
                *(ushort4*)&vt[(((size_t)bb * Hh + hh) * Dd + dd) * Tt + tr] = o;
            }
        return;
    }

#pragma unroll
    for (int mi = 0; mi < 4; ++mi)
#pragma unroll
        for (int ni = 0; ni < 4; ++ni) {
            int col = n0 + wc * 64 + ni * 16 + lq;
            if (col >= N) continue;
            int row = m0 + wr * 64 + mi * 16 + g * 4;
            float bv = bias ? bias[col] : 0.f;
#pragma unroll
            for (int q = 0; q < 4; ++q) {
                float v = acc[mi][ni][q] + bv;
                size_t o = (size_t)(row + q) * N + col;
                if (EPI == 1) v += resid[o];
                if (EPI == 2) v = gelu_f(v);
                st_out(out, o, v);
            }
        }
}

// ---------------------------------------------------------------------------
// MFMA flash attention. Q,K from qkv (bf16); V from pre-transposed vt[b,h,d,T].
// Grid (T/64, B*H), 4 waves x 16 q-rows. Double-buffered K/V fragment LDS;
// ONE raw barrier + end-of-iter vmcnt drain per chunk (P4 is wave-private,
// so no mid-iteration barrier is needed); staged loads get the whole
// QK+softmax+PV phase to land.
// ---------------------------------------------------------------------------
__global__ __launch_bounds__(256)
void attn_mfma(const u16* __restrict__ qkv, const u16* __restrict__ vt,
               u16* __restrict__ y)
{
    __shared__ uint4 KF[2][4][2][64];   // [buf][nt][kslab][lane]
    __shared__ uint4 VF[2][4][2][64];   // [buf][dt][sslab][lane]
    __shared__ u16  P4[4][16][72];      // per-wave P [q][key], padded

    const int tid  = threadIdx.x;
    const int lane = tid & 63;
    const int w    = tid >> 6;
    const int lq   = lane & 15, g = lane >> 4;
    const int qi   = blockIdx.x;
    const int bh   = blockIdx.y;
    const int b    = bh / Hh, h = bh % Hh;
    const int wq0  = qi * 64 + w * 16;
    const size_t base = (size_t)b * Tt * (3 * Cc);

    const u16* qrow = qkv + base + (size_t)(wq0 + lq) * (3 * Cc) + h * Dd;
    bf16x8 qf0 = __builtin_bit_cast(bf16x8, *(const uint4*)(qrow + g * 8));
    bf16x8 qf1 = __builtin_bit_cast(bf16x8, *(const uint4*)(qrow + 32 + g * 8));

    f32x4 yac[4] = {};
    f32x4 mrun = { -1e30f, -1e30f, -1e30f, -1e30f };
    f32x4 lrun = { 0.f, 0.f, 0.f, 0.f };

    const u16* kbase = qkv + base + Cc + h * Dd + (size_t)(w * 16 + lq) * (3 * Cc) + g * 8;
    const u16* vbase = vt + ((size_t)bh * Dd + w * 16 + lq) * Tt + g * 8;

#define STAGE(c, bi)  do {                                              \
        const u16* kp = kbase + (size_t)(c) * 64 * (3 * Cc);            \
        gload16(kp,      &KF[bi][w][0][lane]);                          \
        gload16(kp + 32, &KF[bi][w][1][lane]);                          \
        const u16* vp = vbase + (c) * 64;                               \
        gload16(vp,      &VF[bi][w][0][lane]);                          \
        gload16(vp + 32, &VF[bi][w][1][lane]);                          \
    } while (0)

    STAGE(0, 0);
    WAITVM(0);
    SCHEDB();
    SBAR();
    SCHEDB();

    int buf = 0;
    for (int c = 0; c <= qi; ++c) {
        if (c < qi) STAGE(c + 1, buf ^ 1);

        // S = Q K^T
        f32x4 sc[4] = {};
        __builtin_amdgcn_s_setprio(1);
#pragma unroll
        for (int nt = 0; nt < 4; ++nt) {
            bf16x8 k0 = __builtin_bit_cast(bf16x8, KF[buf][nt][0][lane]);
            bf16x8 k1 = __builtin_bit_cast(bf16x8, KF[buf][nt][1][lane]);
            sc[nt] = __builtin_amdgcn_mfma_f32_16x16x32_bf16(qf0, k0, sc[nt], 0, 0, 0);
            sc[nt] = __builtin_amdgcn_mfma_f32_16x16x32_bf16(qf1, k1, sc[nt], 0, 0, 0);
        }
        __builtin_amdgcn_s_setprio(0);
#pragma unroll
        for (int nt = 0; nt < 4; ++nt) sc[nt] *= 0.125f;

        if (c == qi) {   // diagonal chunk: causal mask
            const int s0 = c * 64;
#pragma unroll
            for (int nt = 0; nt < 4; ++nt)
#pragma unroll
                for (int j = 0; j < 4; ++j) {
                    int key = s0 + nt * 16 + lq;
                    int qr  = wq0 + g * 4 + j;
                    if (key > qr) sc[nt][j] = -1e30f;
                }
        }

        // online softmax (rows = g*4+j, reduce across 16 lanes sharing g)
        f32x4 mx;
#pragma unroll
        for (int j = 0; j < 4; ++j)
            mx[j] = fmaxf(fmaxf(sc[0][j], sc[1][j]), fmaxf(sc[2][j], sc[3][j]));
#pragma unroll
        for (int msk = 1; msk < 16; msk <<= 1)
#pragma unroll
            for (int j = 0; j < 4; ++j)
                mx[j] = fmaxf(mx[j], __shfl_xor(mx[j], msk));

        f32x4 mnew, fac, ps = { 0.f, 0.f, 0.f, 0.f };
#pragma unroll
        for (int j = 0; j < 4; ++j) {
            mnew[j] = fmaxf(mrun[j], mx[j]);
            fac[j]  = __expf(mrun[j] - mnew[j]);
        }
#pragma unroll
        for (int nt = 0; nt < 4; ++nt)
#pragma unroll
            for (int j = 0; j < 4; ++j) {
                float p = __expf(sc[nt][j] - mnew[j]);
                sc[nt][j] = p;
                ps[j] += p;
            }
#pragma unroll
        for (int msk = 1; msk < 16; msk <<= 1)
#pragma unroll
            for (int j = 0; j < 4; ++j)
                ps[j] += __shfl_xor(ps[j], msk);
#pragma unroll
        for (int j = 0; j < 4; ++j) {
            lrun[j] = lrun[j] * fac[j] + ps[j];
            mrun[j] = mnew[j];
        }
#pragma unroll
        for (int dt = 0; dt < 4; ++dt) yac[dt] *= fac;

        // P (wave-private LDS round-trip; compiler orders same-wave ds ops)
#pragma unroll
        for (int nt = 0; nt < 4; ++nt)
#pragma unroll
            for (int j = 0; j < 4; ++j)
                P4[w][g * 4 + j][nt * 16 + lq] = f2bf(sc[nt][j]);

        bf16x8 pa0 = __builtin_bit_cast(bf16x8, *(const uint4*)&P4[w][lq][g * 8]);
        bf16x8 pa1 = __builtin_bit_cast(bf16x8, *(const uint4*)&P4[w][lq][32 + g * 8]);
        __builtin_amdgcn_s_setprio(1);
#pragma unroll
        for (int dt = 0; dt < 4; ++dt) {
            bf16x8 vb0 = __builtin_bit_cast(bf16x8, VF[buf][dt][0][lane]);
            bf16x8 vb1 = __builtin_bit_cast(bf16x8, VF[buf][dt][1][lane]);
            yac[dt] = __builtin_amdgcn_mfma_f32_16x16x32_bf16(pa0, vb0, yac[dt], 0, 0, 0);
            yac[dt] = __builtin_amdgcn_mfma_f32_16x16x32_bf16(pa1, vb1, yac[dt], 0, 0, 0);
        }
        __builtin_amdgcn_s_setprio(0);

        if (c < qi) { WAITVM(0); }   // staged c+1 landed (had whole iter)
        SCHEDB();
        SBAR();
        SCHEDB();
        buf ^= 1;
    }
#undef STAGE

    f32x4 rl;
#pragma unroll
    for (int j = 0; j < 4; ++j) rl[j] = 1.0f / lrun[j];
#pragma unroll
    for (int dt = 0; dt < 4; ++dt)
#pragma unroll
        for (int j = 0; j < 4; ++j)
            y[(size_t)(b * Tt + wq0 + g * 4 + j) * Cc + h * Dd + dt * 16 + lq]
                = f2bf(yac[dt][j] * rl[j]);
}

// ---------------------------------------------------------------------------
// tpred: out[row] = dot(h[row], tp_w)
// ---------------------------------------------------------------------------
__global__ __launch_bounds__(256)
void tpred_kernel(const u16* __restrict__ h, const float* __restrict__ tp,
                  float* __restrict__ out)
{
    const int row  = blockIdx.x * 4 + (threadIdx.x >> 6);
    const int lane = threadIdx.x & 63;
    const u16* hr = h + (size_t)row * Cc;
    float s = 0.f;
#pragma unroll
    for (int j = 0; j < 12; ++j) s += bf2f(hr[lane + (j << 6)]) * tp[lane + (j << 6)];
#pragma unroll
    for (int m = 32; m; m >>= 1) s += __shfl_xor(s, m);
    if (lane == 0) out[row] = s;
}

// ---------------------------------------------------------------------------
extern "C" void kernel_launch(void* const* d_in, const int* in_sizes, int n_in,
                              void* d_out, int out_size, void* d_ws, size_t ws_size,
                              hipStream_t stream)
{
    const int*   idx  = (const int*)d_in[0];
    const float* ts   = (const float*)d_in[1];
    const float* wte  = (const float*)d_in[2];
    const float* freq = (const float*)d_in[3];
    const float* ph   = (const float*)d_in[4];
    const float* wpe  = (const float*)d_in[5];
    const float* ln1w = (const float*)d_in[6];
    const float* ln1b = (const float*)d_in[7];
    const float* qkvw = (const float*)d_in[8];
    const float* qkvb = (const float*)d_in[9];
    const float* pw   = (const float*)d_in[10];
    const float* pb   = (const float*)d_in[11];
    const float* ln2w = (const float*)d_in[12];
    const float* ln2b = (const float*)d_in[13];
    const float* fcw  = (const float*)d_in[14];
    const float* fcb  = (const float*)d_in[15];
    const float* f2w  = (const float*)d_in[16];
    const float* f2b  = (const float*)d_in[17];
    const float* lnfw = (const float*)d_in[18];
    const float* lnfb = (const float*)d_in[19];
    const float* lmw  = (const float*)d_in[20];
    const float* tpw  = (const float*)d_in[21];
    float* out = (float*)d_out;

    const int n_qkvw = 3 * Cc * Cc, n_pw = Cc * Cc, n_fcw = 4 * Cc * Cc;

    // ---- workspace layout ----
    char* p = (char*)d_ws;
    float* x    = (float*)p;               p += (size_t)MTOT * Cc * 4;
    u16*   qkvB = (u16*)p;                 p += (size_t)MTOT * 3 * Cc * 2;
    u16*   VtB  = (u16*)p;                 p += (size_t)Bb * Hh * Dd * Tt * 2;
    u16*   hB   = (u16*)p;                 p += (size_t)MTOT * Cc * 2;
    u16*   yB   = (u16*)p;                 p += (size_t)MTOT * Cc * 2;
    u16*   mbB  = (u16*)p;                 p += (size_t)MTOT * 4 * Cc * 2;
    u16*   lmwB = (u16*)p;                 p += (size_t)Vv * Cc * 2;
    char* wbase = p;

    // big path: all weights converted once (5 dispatches); small: per-layer
    size_t need_big = (size_t)(wbase - (char*)d_ws)
                    + ((size_t)Ll * (n_qkvw + n_pw + 2 * n_fcw)) * 2;
    bool big = ws_size >= need_big;

    u16 *wqA, *wpA, *wfA, *wf2A;
    if (big) {
        wqA  = (u16*)wbase;                wbase += (size_t)Ll * n_qkvw * 2;
        wpA  = (u16*)wbase;                wbase += (size_t)Ll * n_pw * 2;
        wfA  = (u16*)wbase;                wbase += (size_t)Ll * n_fcw * 2;
        wf2A = (u16*)wbase;
    } else {
        wqA  = (u16*)wbase;                wbase += (size_t)n_qkvw * 2;
        wpA  = (u16*)wbase;                wbase += (size_t)n_pw * 2;
        wfA  = (u16*)wbase;                wbase += (size_t)n_fcw * 2;
        wf2A = (u16*)wbase;
    }

    auto cvt = [&](const float* src, u16* dst, size_t n) {
        convert_bf16<<<(int)((n / 4 + 255) / 256), 256, 0, stream>>>(src, dst, (int)(n / 4));
    };

    cvt(lmw, lmwB, (size_t)Vv * Cc);
    if (big) {
        cvt(qkvw, wqA,  (size_t)Ll * n_qkvw);
        cvt(pw,   wpA,  (size_t)Ll * n_pw);
        cvt(fcw,  wfA,  (size_t)Ll * n_fcw);
        cvt(f2w,  wf2A, (size_t)Ll * n_fcw);
    }
    embed_kernel<<<MTOT, 256, 0, stream>>>(idx, ts, wte, freq, ph, wpe, x);

    for (int l = 0; l < Ll; ++l) {
        u16 *wqB, *wpB, *wfB, *wf2B;
        if (big) {
            wqB  = wqA  + (size_t)l * n_qkvw;
            wpB  = wpA  + (size_t)l * n_pw;
            wfB  = wfA  + (size_t)l * n_fcw;
            wf2B = wf2A + (size_t)l * n_fcw;
        } else {
            wqB = wqA; wpB = wpA; wfB = wfA; wf2B = wf2A;
            cvt(qkvw + (size_t)l * n_qkvw, wqB,  n_qkvw);
            cvt(pw   + (size_t)l * n_pw,   wpB,  n_pw);
            cvt(fcw  + (size_t)l * n_fcw,  wfB,  n_fcw);
            cvt(f2w  + (size_t)l * n_fcw,  wf2B, n_fcw);
        }

        ln_kernel<<<MTOT, 256, 0, stream>>>(x, ln1w + l * Cc, ln1b + l * Cc, hB);
        gemm_bf16<3, u16><<<dim3(32, 18), 256, 0, stream>>>(
            hB, wqB, qkvb + (size_t)l * 3 * Cc, nullptr, qkvB, VtB, 3 * Cc, Cc);
        attn_mfma<<<dim3(Tt / 64, Bb * Hh), 256, 0, stream>>>(qkvB, VtB, yB);
        gemm_bf16<1, float><<<dim3(32, 6), 256, 0, stream>>>(
            yB, wpB, pb + (size_t)l * Cc, x, x, nullptr, Cc, Cc);
        ln_kernel<<<MTOT, 256, 0, stream>>>(x, ln2w + l * Cc, ln2b + l * Cc, hB);
        gemm_bf16<2, u16><<<dim3(32, 24), 256, 0, stream>>>(
            hB, wfB, fcb + (size_t)l * 4 * Cc, nullptr, mbB, nullptr, 4 * Cc, Cc);
        gemm_bf16<1, float><<<dim3(32, 6), 256, 0, stream>>>(
            mbB, wf2B, f2b + (size_t)l * Cc, x, x, nullptr, Cc, 4 * Cc);
    }

    ln_kernel<<<MTOT, 256, 0, stream>>>(x, lnfw, lnfb, hB);
    gemm_bf16<0, float><<<dim3(32, 79), 256, 0, stream>>>(
        hB, lmwB, nullptr, nullptr, out, nullptr, Vv, Cc);
    tpred_kernel<<<MTOT / 4, 256, 0, stream>>>(hB, tpw, out + (size_t)MTOT * Vv);
}